// Round 1
// baseline (509.509 us; speedup 1.0000x reference)
//
#include <hip/hip_runtime.h>

typedef _Float16 hv8 __attribute__((ext_vector_type(8)));  // 8 fp16 = 4 VGPRs MFMA A/B frag
typedef float    fv4 __attribute__((ext_vector_type(4)));  // 4 fp32 MFMA C/D frag

#define DEVI __device__ __forceinline__

static constexpr int T_   = 200;
static constexpr int ROWS = 16;     // real batch rows per block == full MFMA M-dim (256 blocks, 1/CU)
static constexpr int WS   = 72;     // row stride in halfs (144 B: 16B-aligned, 2-way bank alias = free)
// A-slab offsets in halfs (carved into weight pool after B-frags move to registers)
static constexpr int A1o = 0;                 // [16][WS]: x(0:36) | bias1(36)=1 | pad | h1(48:64)
static constexpr int A2o = 16 * WS;           // [2][16][WS]: h1(0:16) | h2(16:48) | bias(48)=1 | pad
static constexpr int A3o = A2o + 2 * 16 * WS; // [2][16][WS]: h2(0:32) | h3(32:48) | bias(48)=1 | pad
static constexpr int A_TOTAL = A3o + 2 * 16 * WS;  // 5760 halfs

#if __has_builtin(__builtin_amdgcn_rcpf)
DEVI float frcp(float x) { return __builtin_amdgcn_rcpf(x); }
#else
DEVI float frcp(float x) { return 1.0f / x; }
#endif
DEVI float fsig(float x)  { return frcp(1.0f + __expf(-x)); }                          // inf-safe -> 0/1
DEVI float ftanh(float x) { float e = __expf(2.0f * x); return 1.0f - 2.0f * frcp(e + 1.0f); } // -> -1/1

DEVI unsigned int pk2h(float a, float b) {     // pack two fp32 -> fp16x2 (RNE via v_cvt_f16_f32)
    union { _Float16 h[2]; unsigned int u; } cv;
    cv.h[0] = (_Float16)a; cv.h[1] = (_Float16)b;
    return cv.u;
}

// ---------------- fused 3-layer LSTM + collapsed linear head ----------------
// 256 blocks x 256 threads; block owns 16 batch rows (all 16 MFMA M-rows real);
// 4 waves = layer pipeline stages (w0: L1(t=s), w1/w2: L2(t=s-1) unit-halves,
// w3: L3(t=s-2)); one barrier per step.
__global__ __launch_bounds__(256, 2) void lstm_fused(
    const float* __restrict__ xg,
    const float* __restrict__ Wih1, const float* __restrict__ Whh1,
    const float* __restrict__ bih1, const float* __restrict__ bhh1,
    const float* __restrict__ Wih2, const float* __restrict__ Whh2,
    const float* __restrict__ bih2, const float* __restrict__ bhh2,
    const float* __restrict__ Wih3, const float* __restrict__ Whh3,
    const float* __restrict__ bih3, const float* __restrict__ bhh3,
    const float* __restrict__ W_fc1, const float* __restrict__ b_fc1,
    const float* __restrict__ W_fc2, const float* __restrict__ b_fc2,
    const float* __restrict__ W_cls, const float* __restrict__ b_cls,
    float* __restrict__ outp)
{
    // poolH: weights [256 rows][WS] fp16 during prologue; A-slabs carved in afterwards
    __shared__ __align__(16) _Float16 poolH[256 * WS];       // 36864 B
    __shared__ unsigned int xst[2 * 16 * ROWS * 18];         // x chunks fp16x2-packed: [par][t&15][row][18] = 36864 B
    __shared__ float T2s[512];   // [32][16] = W_fc2 @ W_fc1
    __shared__ float t2vs[32];   // b_fc2 + W_fc2 @ b_fc1
    __shared__ float Msh[96];    // [16][6] collapsed head matrix
    __shared__ float vsh[6];     // collapsed head bias

    const int tid  = threadIdx.x;
    const int wid  = tid >> 6;       // 0=L1, 1/2=L2 halves, 3=L3
    const int lane = tid & 63;
    const int nl   = lane & 15;
    const int quad = lane >> 4;
    const int b0   = blockIdx.x * ROWS;

    // ---- stage weights (fp32 -> fp16) as B^T rows [n][k]; bias folded in as a weight column ----
    // w0 (L1): k = [Wih1(0:36) | bias(36) | 0 | Whh1(48:64)]
    // w1/w2 (L2 half): k = [Wih2(0:16) | Whh2(16:48) | bias(48) | 0]
    // w3 (L3): k = [Wih3(0:32) | Whh3(32:48) | bias(48) | 0]
    for (int idx = tid; idx < 256 * WS; idx += 256) {
        int n = idx / WS, k = idx - n * WS;
        int w = n >> 6, r = n & 63;
        int g = r >> 4, u = r & 15;
        float v = 0.f;
        if (w == 0) {
            int row = g * 16 + u;
            if (k < 36)       v = Wih1[row * 36 + k];
            else if (k == 36) v = bih1[row] + bhh1[row];
            else if (k >= 48 && k < 64) v = Whh1[row * 16 + (k - 48)];
        } else if (w <= 2) {
            int row = g * 32 + (w - 1) * 16 + u;
            if (k < 16)       v = Wih2[row * 16 + k];
            else if (k < 48)  v = Whh2[row * 32 + (k - 16)];
            else if (k == 48) v = bih2[row] + bhh2[row];
        } else {
            int row = g * 16 + u;
            if (k < 32)       v = Wih3[row * 32 + k];
            else if (k < 48)  v = Whh3[row * 16 + (k - 32)];
            else if (k == 48) v = bih3[row] + bhh3[row];
        }
        poolH[idx] = (_Float16)v;
    }
    // head: T2 = W_fc2 @ W_fc1 (fp32; 24KB weights, L2-resident)
    for (int idx = tid; idx < 512; idx += 256) {
        int b = idx >> 4, u = idx & 15;
        float acc = 0.f;
        for (int a = 0; a < 128; ++a) acc += W_fc2[b * 128 + a] * W_fc1[a * 16 + u];
        T2s[idx] = acc;
    }
    if (tid < 32) {
        float acc = b_fc2[tid];
        for (int a = 0; a < 128; ++a) acc += W_fc2[tid * 128 + a] * b_fc1[a];
        t2vs[tid] = acc;
    }
    __syncthreads();

    // ---- per-wave register-resident B-frags: lane holds B[k=kt*32+quad*8+j][n=nt*16+nl] ----
    hv8 Bf[2][4];
    #pragma unroll
    for (int kt = 0; kt < 2; ++kt)
        #pragma unroll
        for (int nt = 0; nt < 4; ++nt)
            Bf[kt][nt] = *(const hv8*)&poolH[(wid * 64 + nt * 16 + nl) * WS + kt * 32 + quad * 8];
    // collapsed head: M[u][j] = sum_b Wc[j][b]*T2[b][u];  v[j] = bc[j] + sum_b Wc[j][b]*t2v[b]
    if (tid < 96) {
        int u = tid / 6, j = tid - (tid / 6) * 6;
        float acc = 0.f;
        for (int b = 0; b < 32; ++b) acc += W_cls[j * 32 + b] * T2s[b * 16 + u];
        Msh[u * 6 + j] = acc;
    }
    if (tid < 6) {
        float acc = b_cls[tid];
        for (int b = 0; b < 32; ++b) acc += W_cls[tid * 32 + b] * t2vs[b];
        vsh[tid] = acc;
    }
    __syncthreads();   // weights now in registers; pool reusable

    // ---- zero A-slabs, set bias-1.0 columns, stage x chunk 0 ----
    for (int idx = tid; idx < A_TOTAL; idx += 256) poolH[idx] = (_Float16)0.f;
    {   // refill chunk 0 (t=0..15): 16 rows * 16 t * 18 = 4608 u32 = 18/thread
        const float2* xw2 = (const float2*)xg;
        #pragma unroll
        for (int i = 0; i < 18; ++i) {
            int j = tid + i * 256;
            int row = j / 288, rem = j - row * 288;
            int tl = rem / 18, p = rem - tl * 18;
            float2 xv = xw2[((size_t)(b0 + row) * T_ + tl) * 18 + p];
            xst[(tl * ROWS + row) * 18 + p] = pk2h(xv.x, xv.y);
        }
    }
    __syncthreads();
    // bias columns (all 16 M-rows, both parities) + x(0) into A1
    if (tid < 16)  poolH[A1o + tid * WS + 36] = (_Float16)1.0f;
    if (tid < 64) {
        int buf = tid >> 5, par = (tid >> 4) & 1, row = tid & 15;
        poolH[(buf ? A3o : A2o) + par * 16 * WS + row * WS + 48] = (_Float16)1.0f;
    }
    for (int idx = tid; idx < ROWS * 18; idx += 256) {   // u32 view: A1 row stride = WS/2 = 36
        int row = idx / 18, p = idx - (idx / 18) * 18;
        ((unsigned int*)poolH)[row * 36 + p] = xst[(0 * ROWS + row) * 18 + p];
    }
    __syncthreads();

    float c_st[4] = {0.f, 0.f, 0.f, 0.f};  // fp32 cell state: 4 M-rows x 1 unit per lane

    for (int s = 0; s < T_ + 2; ++s) {
        const int rd = (s - 1) & 1, wr = s & 1;
        // chunk refill: at interval start stage chunk (s/16 + 1) into other parity;
        // loads drain at this step's end barrier, hidden under compute.
        if ((s & 15) == 0) {
            int cn = (s >> 4) + 1;
            if (cn <= 12) {
                const float2* xw2 = (const float2*)xg;
                unsigned int* dst = &xst[(cn & 1) * 16 * ROWS * 18];
                int tbase = cn * 16;
                #pragma unroll
                for (int i = 0; i < 18; ++i) {
                    int j = tid + i * 256;
                    int row = j / 288, rem = j - row * 288;
                    int tl = rem / 18, p = rem - tl * 18;
                    int t = tbase + tl;
                    if (t < T_) {
                        float2 xv = xw2[((size_t)(b0 + row) * T_ + t) * 18 + p];
                        dst[(tl * ROWS + row) * 18 + p] = pk2h(xv.x, xv.y);
                    }
                }
            }
        }
        bool act;
        if (wid == 0)      act = (s < T_);                 // L1 at t=s
        else if (wid <= 2) act = (s >= 1 && s <= T_);      // L2 at t=s-1
        else               act = (s >= 2);                 // L3 at t=s-2
        if (act) {
            int abase;
            if (wid == 0)      abase = A1o;
            else if (wid <= 2) abase = A2o + rd * 16 * WS;
            else               abase = A3o + rd * 16 * WS;
            hv8 a0 = *(const hv8*)&poolH[abase + nl * WS +      quad * 8];
            hv8 a1 = *(const hv8*)&poolH[abase + nl * WS + 32 + quad * 8];
            // wave0: copy x(s+1) xstage -> A1 (after own frag reads; in-wave LDS order)
            if (wid == 0 && s + 1 < T_) {
                int t = s + 1;
                const unsigned int* src = &xst[((t >> 4) & 1) * 16 * ROWS * 18 + (t & 15) * ROWS * 18];
                unsigned int* dstA = (unsigned int*)poolH;
                #pragma unroll
                for (int i = 0; i < 5; ++i) {
                    int idx = i * 64 + lane;
                    if (idx < ROWS * 18) {
                        int row = idx / 18, p = idx - (idx / 18) * 18;
                        dstA[row * 36 + p] = src[idx];
                    }
                }
            }
            fv4 C[4] = {(fv4){0,0,0,0}, (fv4){0,0,0,0}, (fv4){0,0,0,0}, (fv4){0,0,0,0}};
            #pragma unroll
            for (int nt = 0; nt < 4; ++nt) C[nt] = __builtin_amdgcn_mfma_f32_16x16x32_f16(a0, Bf[0][nt], C[nt], 0, 0, 0);
            #pragma unroll
            for (int nt = 0; nt < 4; ++nt) C[nt] = __builtin_amdgcn_mfma_f32_16x16x32_f16(a1, Bf[1][nt], C[nt], 0, 0, 0);
            // C[nt][r] = gate nt (i,f,g,o) for M-row quad*4+r, unit nl (bias included via 1.0-column)
            #pragma unroll
            for (int r = 0; r < 4; ++r) {
                int m = quad * 4 + r;
                float gi = fsig(C[0][r]);
                float gf = fsig(C[1][r]);
                float gg = ftanh(C[2][r]);
                float go = fsig(C[3][r]);
                float c  = gf * c_st[r] + gi * gg;
                c_st[r] = c;
                _Float16 hh = (_Float16)(go * ftanh(c));
                if (wid == 0) {
                    poolH[A1o + m * WS + 48 + nl] = hh;                    // own recurrence
                    poolH[A2o + wr * 16 * WS + m * WS + nl] = hh;          // feed L2
                } else if (wid <= 2) {
                    int ug = (wid - 1) * 16 + nl;
                    poolH[A2o + wr * 16 * WS + m * WS + 16 + ug] = hh;     // own recurrence
                    poolH[A3o + wr * 16 * WS + m * WS + ug] = hh;          // feed L3
                } else {
                    poolH[A3o + wr * 16 * WS + m * WS + 32 + nl] = hh;     // own recurrence
                }
            }
        }
        __syncthreads();
    }

    // ---- epilogue: out[b][j] = h3(T-1) . M[:,j] + v[j]  (h3 in A3 parity (T_+1)&1) ----
    if (tid < ROWS * 6) {
        int row = tid / 6, j = tid - (tid / 6) * 6;
        float acc = vsh[j];
        const int hb = A3o + ((T_ + 1) & 1) * 16 * WS + row * WS + 32;
        #pragma unroll
        for (int u = 0; u < 16; ++u)
            acc += (float)poolH[hb + u] * Msh[u * 6 + j];
        outp[(b0 + row) * 6 + j] = acc;
    }
}

extern "C" void kernel_launch(void* const* d_in, const int* in_sizes, int n_in,
                              void* d_out, int out_size, void* d_ws, size_t ws_size,
                              hipStream_t stream) {
    const float* x     = (const float*)d_in[0];
    const float* Wih1  = (const float*)d_in[1];
    const float* Whh1  = (const float*)d_in[2];
    const float* bih1  = (const float*)d_in[3];
    const float* bhh1  = (const float*)d_in[4];
    const float* Wih2  = (const float*)d_in[5];
    const float* Whh2  = (const float*)d_in[6];
    const float* bih2  = (const float*)d_in[7];
    const float* bhh2  = (const float*)d_in[8];
    const float* Wih3  = (const float*)d_in[9];
    const float* Whh3  = (const float*)d_in[10];
    const float* bih3  = (const float*)d_in[11];
    const float* bhh3  = (const float*)d_in[12];
    const float* W_fc1 = (const float*)d_in[13];
    const float* b_fc1 = (const float*)d_in[14];
    const float* W_fc2 = (const float*)d_in[15];
    const float* b_fc2 = (const float*)d_in[16];
    const float* W_cls = (const float*)d_in[17];
    const float* b_cls = (const float*)d_in[18];

    lstm_fused<<<256, 256, 0, stream>>>(x,
        Wih1, Whh1, bih1, bhh1,
        Wih2, Whh2, bih2, bhh2,
        Wih3, Whh3, bih3, bhh3,
        W_fc1, b_fc1, W_fc2, b_fc2, W_cls, b_cls,
        (float*)d_out);
}

// Round 2
// 474.643 us; speedup vs baseline: 1.0735x; 1.0735x over previous
//
#include <hip/hip_runtime.h>

typedef _Float16 hv8 __attribute__((ext_vector_type(8)));  // 8 fp16 = 4 VGPRs MFMA A/B frag
typedef float    fv4 __attribute__((ext_vector_type(4)));  // 4 fp32 MFMA C/D frag

#define DEVI __device__ __forceinline__

static constexpr int T_   = 200;
static constexpr int ROWS = 8;      // batch rows per block (512 blocks, 2 blocks/CU)
static constexpr int WS   = 72;     // row stride in halfs (144 B: 16B-aligned)
// A-slab offsets in halfs. G=2 double-pump: A2/A3 have 4 slabs [par*2+g].
static constexpr int A1o = 0;                 // [16][WS]: x(0:36) | bias1(36)=1 | pad | h1(48:64)
static constexpr int A2o = 16 * WS;           // [4][16][WS]: h1(0:16) | h2(16:48) | bias(48)=1
static constexpr int A3o = A2o + 4 * 16 * WS; // [4][16][WS]: h2(0:32) | h3(32:48) | bias(48)=1
static constexpr int A_TOTAL = A3o + 4 * 16 * WS;  // 10368 halfs = 20736 B (fits in weight pool)

#if __has_builtin(__builtin_amdgcn_rcpf)
DEVI float frcp(float x) { return __builtin_amdgcn_rcpf(x); }
#else
DEVI float frcp(float x) { return 1.0f / x; }
#endif
DEVI float fsig(float x)  { return frcp(1.0f + __expf(-x)); }                          // inf-safe -> 0/1
DEVI float ftanh(float x) { float e = __expf(2.0f * x); return 1.0f - 2.0f * frcp(e + 1.0f); } // -> -1/1

DEVI unsigned int pk2h(float a, float b) {     // pack two fp32 -> fp16x2 (RNE via v_cvt_f16_f32)
    union { _Float16 h[2]; unsigned int u; } cv;
    cv.h[0] = (_Float16)a; cv.h[1] = (_Float16)b;
    return cv.u;
}

// ---------------- fused 3-layer LSTM + collapsed linear head ----------------
// 512 blocks x 256 threads; block owns 8 batch rows; 4 waves = layer pipeline
// stages. G=2 double-pump: each barrier interval s covers TWO timesteps per
// layer (w0: L1 t=2s,2s+1; w1/w2: L2 t=2s-2,2s-1; w3: L3 t=2s-4,2s-3).
// Own-layer recurrence between the two timesteps is in-wave LDS ordering
// (no barrier); inter-layer handoff is double-buffered by interval parity.
// One barrier per interval => 102 barriers instead of 202.
__global__ __launch_bounds__(256, 2) void lstm_fused(
    const float* __restrict__ xg,
    const float* __restrict__ Wih1, const float* __restrict__ Whh1,
    const float* __restrict__ bih1, const float* __restrict__ bhh1,
    const float* __restrict__ Wih2, const float* __restrict__ Whh2,
    const float* __restrict__ bih2, const float* __restrict__ bhh2,
    const float* __restrict__ Wih3, const float* __restrict__ Whh3,
    const float* __restrict__ bih3, const float* __restrict__ bhh3,
    const float* __restrict__ W_fc1, const float* __restrict__ b_fc1,
    const float* __restrict__ W_fc2, const float* __restrict__ b_fc2,
    const float* __restrict__ W_cls, const float* __restrict__ b_cls,
    float* __restrict__ outp)
{
    // poolH: weights [256 rows][WS] fp16 during prologue; A-slabs carved in afterwards
    __shared__ __align__(16) _Float16 poolH[256 * WS];       // 36864 B
    __shared__ unsigned int xst[2 * 16 * ROWS * 18];         // x chunks fp16x2-packed: [par][t&15][row][18]
    __shared__ float T2s[512];   // [32][16] = W_fc2 @ W_fc1
    __shared__ float t2vs[32];   // b_fc2 + W_fc2 @ b_fc1
    __shared__ float Msh[96];    // [16][6] collapsed head matrix
    __shared__ float vsh[6];     // collapsed head bias

    const int tid  = threadIdx.x;
    const int wid  = tid >> 6;       // 0=L1, 1/2=L2 halves, 3=L3
    const int lane = tid & 63;
    const int nl   = lane & 15;
    const int quad = lane >> 4;
    const int b0   = blockIdx.x * ROWS;

    // ---- stage weights (fp32 -> fp16) as B^T rows [n][k]; bias folded in as a weight column ----
    // w0 (L1): k = [Wih1(0:36) | bias(36) | 0 | Whh1(48:64)]
    // w1/w2 (L2 half): k = [Wih2(0:16) | Whh2(16:48) | bias(48) | 0]
    // w3 (L3): k = [Wih3(0:32) | Whh3(32:48) | bias(48) | 0]
    for (int idx = tid; idx < 256 * WS; idx += 256) {
        int n = idx / WS, k = idx - n * WS;
        int w = n >> 6, r = n & 63;
        int g = r >> 4, u = r & 15;
        float v = 0.f;
        if (w == 0) {
            int row = g * 16 + u;
            if (k < 36)       v = Wih1[row * 36 + k];
            else if (k == 36) v = bih1[row] + bhh1[row];
            else if (k >= 48 && k < 64) v = Whh1[row * 16 + (k - 48)];
        } else if (w <= 2) {
            int row = g * 32 + (w - 1) * 16 + u;
            if (k < 16)       v = Wih2[row * 16 + k];
            else if (k < 48)  v = Whh2[row * 32 + (k - 16)];
            else if (k == 48) v = bih2[row] + bhh2[row];
        } else {
            int row = g * 16 + u;
            if (k < 32)       v = Wih3[row * 32 + k];
            else if (k < 48)  v = Whh3[row * 16 + (k - 32)];
            else if (k == 48) v = bih3[row] + bhh3[row];
        }
        poolH[idx] = (_Float16)v;
    }
    // head: T2 = W_fc2 @ W_fc1 (fp32; 24KB weights, L2-resident)
    for (int idx = tid; idx < 512; idx += 256) {
        int b = idx >> 4, u = idx & 15;
        float acc = 0.f;
        for (int a = 0; a < 128; ++a) acc += W_fc2[b * 128 + a] * W_fc1[a * 16 + u];
        T2s[idx] = acc;
    }
    if (tid < 32) {
        float acc = b_fc2[tid];
        for (int a = 0; a < 128; ++a) acc += W_fc2[tid * 128 + a] * b_fc1[a];
        t2vs[tid] = acc;
    }
    __syncthreads();

    // ---- per-wave register-resident B-frags: lane holds B[k=kt*32+quad*8+j][n=nt*16+nl] ----
    hv8 Bf[2][4];
    #pragma unroll
    for (int kt = 0; kt < 2; ++kt)
        #pragma unroll
        for (int nt = 0; nt < 4; ++nt)
            Bf[kt][nt] = *(const hv8*)&poolH[(wid * 64 + nt * 16 + nl) * WS + kt * 32 + quad * 8];
    // collapsed head: M[u][j] = sum_b Wc[j][b]*T2[b][u];  v[j] = bc[j] + sum_b Wc[j][b]*t2v[b]
    if (tid < 96) {
        int u = tid / 6, j = tid - (tid / 6) * 6;
        float acc = 0.f;
        for (int b = 0; b < 32; ++b) acc += W_cls[j * 32 + b] * T2s[b * 16 + u];
        Msh[u * 6 + j] = acc;
    }
    if (tid < 6) {
        float acc = b_cls[tid];
        for (int b = 0; b < 32; ++b) acc += W_cls[tid * 32 + b] * t2vs[b];
        vsh[tid] = acc;
    }
    __syncthreads();   // weights now in registers; pool reusable

    // ---- zero A-slabs, set bias-1.0 columns, stage x chunk 0 ----
    for (int idx = tid; idx < A_TOTAL; idx += 256) poolH[idx] = (_Float16)0.f;
    {   // refill chunk 0 (t=0..15): 8 rows * 16 t * 18 = 2304 u32 = 9/thread
        const float2* xw2 = (const float2*)xg;
        #pragma unroll
        for (int i = 0; i < 9; ++i) {
            int j = tid + i * 256;
            int row = j / 288, rem = j - row * 288;
            int tl = rem / 18, p = rem - tl * 18;
            float2 xv = xw2[((size_t)(b0 + row) * T_ + tl) * 18 + p];
            xst[(tl * ROWS + row) * 18 + p] = pk2h(xv.x, xv.y);
        }
    }
    __syncthreads();
    // bias columns (A1 col36; A2/A3 all 4 slabs col48) + x(0) into A1
    if (tid < 16)  poolH[A1o + tid * WS + 36] = (_Float16)1.0f;
    if (tid < 128) {
        int buf = tid >> 6, slab = (tid >> 4) & 3, row = tid & 15;
        poolH[(buf ? A3o : A2o) + slab * 16 * WS + row * WS + 48] = (_Float16)1.0f;
    }
    if (tid < ROWS * 18) {   // u32 view: A1 row stride = WS/2 = 36
        int row = tid / 18, p = tid - (tid / 18) * 18;
        ((unsigned int*)poolH)[row * 36 + p] = xst[(0 * ROWS + row) * 18 + p];
    }
    __syncthreads();

    float c_st[4] = {0.f, 0.f, 0.f, 0.f};  // fp32 cell state: 4 M-rows x 1 unit per lane

    const int NI = T_ / 2 + 2;   // 102 barrier intervals
    for (int s = 0; s < NI; ++s) {
        const int p = s & 1, np = p ^ 1;
        // chunk refill: every 8 intervals (=16 timesteps) stage next chunk into
        // other parity; drains at this interval's end barrier, 7 intervals slack.
        if ((s & 7) == 0) {
            int cn = (s >> 3) + 1;
            if (cn <= 12) {
                const float2* xw2 = (const float2*)xg;
                unsigned int* dst = &xst[(cn & 1) * 16 * ROWS * 18];
                int tbase = cn * 16;
                #pragma unroll
                for (int i = 0; i < 9; ++i) {
                    int j = tid + i * 256;
                    int row = j / 288, rem = j - row * 288;
                    int tl = rem / 18, pp = rem - tl * 18;
                    int t = tbase + tl;
                    if (t < T_) {
                        float2 xv = xw2[((size_t)(b0 + row) * T_ + t) * 18 + pp];
                        dst[(tl * ROWS + row) * 18 + pp] = pk2h(xv.x, xv.y);
                    }
                }
            }
        }
        bool act;
        if (wid == 0)      act = (s < T_ / 2);                 // L1: t=2s,2s+1
        else if (wid <= 2) act = (s >= 1 && s <= T_ / 2);      // L2: t=2s-2,2s-1
        else               act = (s >= 2);                     // L3: t=2s-4,2s-3
        if (act) {
            #pragma unroll
            for (int g = 0; g < 2; ++g) {
                int abase;
                if (wid == 0)      abase = A1o;
                else if (wid <= 2) abase = A2o + (p * 2 + g) * 16 * WS;
                else               abase = A3o + (p * 2 + g) * 16 * WS;
                hv8 a0 = *(const hv8*)&poolH[abase + nl * WS +      quad * 8];
                hv8 a1 = *(const hv8*)&poolH[abase + nl * WS + 32 + quad * 8];
                // wave0: copy x(t+1) xstage -> A1 (after own frag reads; in-wave LDS order)
                if (wid == 0) {
                    int t1 = 2 * s + g + 1;
                    if (t1 < T_) {
                        const unsigned int* src = &xst[((t1 >> 4) & 1) * 16 * ROWS * 18 + (t1 & 15) * ROWS * 18];
                        unsigned int* dstA = (unsigned int*)poolH;
                        #pragma unroll
                        for (int i = 0; i < 3; ++i) {
                            int idx = i * 64 + lane;
                            if (idx < ROWS * 18) {
                                int row = idx / 18, pp = idx - (idx / 18) * 18;
                                dstA[row * 36 + pp] = src[idx];
                            }
                        }
                    }
                }
                fv4 C[4] = {(fv4){0,0,0,0}, (fv4){0,0,0,0}, (fv4){0,0,0,0}, (fv4){0,0,0,0}};
                #pragma unroll
                for (int nt = 0; nt < 4; ++nt) C[nt] = __builtin_amdgcn_mfma_f32_16x16x32_f16(a0, Bf[0][nt], C[nt], 0, 0, 0);
                #pragma unroll
                for (int nt = 0; nt < 4; ++nt) C[nt] = __builtin_amdgcn_mfma_f32_16x16x32_f16(a1, Bf[1][nt], C[nt], 0, 0, 0);
                // own-recurrence target slab for L2/L3: g=0 -> (p,1) same interval; g=1 -> (np,0) next interval
                const int os = g ? (np * 2 + 0) : (p * 2 + 1);
                // C[nt][r] = gate nt (i,f,g,o) for M-row quad*4+r, unit nl (bias via 1.0-column)
                #pragma unroll
                for (int r = 0; r < 4; ++r) {
                    int m = quad * 4 + r;
                    float gi = fsig(C[0][r]);
                    float gf = fsig(C[1][r]);
                    float gg = ftanh(C[2][r]);
                    float go = fsig(C[3][r]);
                    float c  = gf * c_st[r] + gi * gg;
                    c_st[r] = c;
                    _Float16 hh = (_Float16)(go * ftanh(c));
                    if (wid == 0) {
                        poolH[A1o + m * WS + 48 + nl] = hh;                          // own recurrence (in-place)
                        poolH[A2o + (np * 2 + g) * 16 * WS + m * WS + nl] = hh;      // feed L2 next interval
                    } else if (wid <= 2) {
                        int ug = (wid - 1) * 16 + nl;
                        poolH[A2o + os * 16 * WS + m * WS + 16 + ug] = hh;           // own recurrence
                        poolH[A3o + (np * 2 + g) * 16 * WS + m * WS + ug] = hh;      // feed L3 next interval
                    } else {
                        poolH[A3o + os * 16 * WS + m * WS + 32 + nl] = hh;           // own recurrence
                    }
                }
            }
        }
        __syncthreads();
    }

    // ---- epilogue: out[b][j] = h3(T-1) . M[:,j] + v[j] ----
    // final h3 written at s=NI-1=101, g=1 -> slab np*2+0 = 0 (par(101)=1)
    if (tid < ROWS * 6) {
        int row = tid / 6, j = tid - (tid / 6) * 6;
        float acc = vsh[j];
        const int hb = A3o + 0 * 16 * WS + row * WS + 32;
        #pragma unroll
        for (int u = 0; u < 16; ++u)
            acc += (float)poolH[hb + u] * Msh[u * 6 + j];
        outp[(b0 + row) * 6 + j] = acc;
    }
}

extern "C" void kernel_launch(void* const* d_in, const int* in_sizes, int n_in,
                              void* d_out, int out_size, void* d_ws, size_t ws_size,
                              hipStream_t stream) {
    const float* x     = (const float*)d_in[0];
    const float* Wih1  = (const float*)d_in[1];
    const float* Whh1  = (const float*)d_in[2];
    const float* bih1  = (const float*)d_in[3];
    const float* bhh1  = (const float*)d_in[4];
    const float* Wih2  = (const float*)d_in[5];
    const float* Whh2  = (const float*)d_in[6];
    const float* bih2  = (const float*)d_in[7];
    const float* bhh2  = (const float*)d_in[8];
    const float* Wih3  = (const float*)d_in[9];
    const float* Whh3  = (const float*)d_in[10];
    const float* bih3  = (const float*)d_in[11];
    const float* bhh3  = (const float*)d_in[12];
    const float* W_fc1 = (const float*)d_in[13];
    const float* b_fc1 = (const float*)d_in[14];
    const float* W_fc2 = (const float*)d_in[15];
    const float* b_fc2 = (const float*)d_in[16];
    const float* W_cls = (const float*)d_in[17];
    const float* b_cls = (const float*)d_in[18];

    lstm_fused<<<512, 256, 0, stream>>>(x,
        Wih1, Whh1, bih1, bhh1,
        Wih2, Whh2, bih2, bhh2,
        Wih3, Whh3, bih3, bhh3,
        W_fc1, b_fc1, W_fc2, b_fc2, W_cls, b_cls,
        (float*)d_out);
}

// Round 3
// 435.885 us; speedup vs baseline: 1.1689x; 1.0889x over previous
//
#include <hip/hip_runtime.h>

typedef _Float16 hv8 __attribute__((ext_vector_type(8)));  // 8 fp16 = 4 VGPRs MFMA A/B frag
typedef float    fv4 __attribute__((ext_vector_type(4)));  // 4 fp32 MFMA C/D frag
typedef unsigned int u32;

#define DEVI __device__ __forceinline__

static constexpr int T_   = 200;
static constexpr int ROWS = 8;      // batch rows per block (512 blocks, 2 blocks/CU)
static constexpr int WS   = 72;     // weight row stride in halfs (144 B, 16B-aligned)
static constexpr int BTOT = 4096;

// Feed slabs carved into poolH after weight frags move to registers (offsets in halfs).
// All feeds are [batch][unit] fp16 so producer writes packed u32 pairs and consumer
// reads contiguous hv8 per lane (act B-frag = act[k=unit][batch=nl]).
static constexpr int F1o = 0;      // [2 par][2 g][16 b][16 u]  h1 feed  w0 -> w1,w2
static constexpr int F2o = 1024;   // [2 par][2 g][16 b][32 u]  h2 feed  w1,w2 -> w3
static constexpr int XAo = 3072;   // [2 slot][16 b][16 u]      w1 own h2 (units 0:16)  read by w2
static constexpr int XBo = 3584;   // [2 slot][16 b][16 u]      w2 own h2 (units 16:32) read by w1
static constexpr int F3o = 4096;   // [2 slot][16 b][16 u]      h3 (epilogue reads slot 1)
static constexpr int F_TOTAL = 4608;

#if __has_builtin(__builtin_amdgcn_rcpf)
DEVI float frcp(float x) { return __builtin_amdgcn_rcpf(x); }
#else
DEVI float frcp(float x) { return 1.0f / x; }
#endif
DEVI float fsig(float x)  { return frcp(1.0f + __expf(-x)); }                          // inf-safe -> 0/1
DEVI float ftanh(float x) { float e = __expf(2.0f * x); return 1.0f - 2.0f * frcp(e + 1.0f); } // -> -1/1

DEVI u32 pk2h(float a, float b) {     // pack two fp32 -> fp16x2 (RNE via v_cvt_f16_f32)
    union { _Float16 h[2]; u32 u; } cv;
    cv.h[0] = (_Float16)a; cv.h[1] = (_Float16)b;
    return cv.u;
}

union HU { hv8 h; u32 u[4]; };

// ---------------- fused 3-layer LSTM + collapsed linear head ----------------
// Swapped-operand MFMA: A = weights (m=gate-row), B = activations (k=feature, n=batch).
// Lane (quad,nl) produces h[units quad*4..+3][batch nl]; the next-step B-frag needs
// units along k at the SAME nl, so the recurrence is 4 ds_bpermute of packed fp16
// pairs -- no LDS round trip on the critical path. x is loaded HBM->regs directly
// (2-step prefetch). Inter-layer handoff via small LDS feeds, double-buffered by
// interval parity (one barrier per 2 timesteps, G=2 as round 2).
__global__ __launch_bounds__(256, 2) void lstm_fused(
    const float* __restrict__ xg,
    const float* __restrict__ Wih1, const float* __restrict__ Whh1,
    const float* __restrict__ bih1, const float* __restrict__ bhh1,
    const float* __restrict__ Wih2, const float* __restrict__ Whh2,
    const float* __restrict__ bih2, const float* __restrict__ bhh2,
    const float* __restrict__ Wih3, const float* __restrict__ Whh3,
    const float* __restrict__ bih3, const float* __restrict__ bhh3,
    const float* __restrict__ W_fc1, const float* __restrict__ b_fc1,
    const float* __restrict__ W_fc2, const float* __restrict__ b_fc2,
    const float* __restrict__ W_cls, const float* __restrict__ b_cls,
    float* __restrict__ outp)
{
    // poolH: weights [256 rows][WS] fp16 during prologue; feed slabs carved in afterwards
    __shared__ __align__(16) _Float16 poolH[256 * WS];       // 36864 B
    __shared__ float T2s[512];   // [32][16] = W_fc2 @ W_fc1
    __shared__ float t2vs[32];   // b_fc2 + W_fc2 @ b_fc1
    __shared__ float Msh[96];    // [16][6] collapsed head matrix
    __shared__ float vsh[6];     // collapsed head bias

    const int tid  = threadIdx.x;
    const int wid  = tid >> 6;       // 0=L1, 1/2=L2 halves, 3=L3
    const int lane = tid & 63;
    const int nl   = lane & 15;
    const int quad = lane >> 4;
    const int b0   = blockIdx.x * ROWS;

    // ---- stage weights (fp32 -> fp16) as rows [gate-row][k]; bias folded as a column ----
    // w0 (L1): k = [Wih1(0:36) | bias(36) | 0 | Whh1(48:64)]
    // w1 (L2 units 0:16):  k = [Wih2(0:16) | Whh2 own u0:16 (16:32) | other u16:32 (32:48) | bias(48) | 0]
    // w2 (L2 units 16:32): k = [Wih2(0:16) | Whh2 own u16:32 (16:32) | other u0:16 (32:48) | bias(48) | 0]
    // w3 (L3): k = [Wih3(0:32) | Whh3(32:48) | bias(48) | 0]
    for (int idx = tid; idx < 256 * WS; idx += 256) {
        int n = idx / WS, k = idx - n * WS;
        int w = n >> 6, r = n & 63;
        int g = r >> 4, u = r & 15;
        float v = 0.f;
        if (w == 0) {
            int row = g * 16 + u;
            if (k < 36)       v = Wih1[row * 36 + k];
            else if (k == 36) v = bih1[row] + bhh1[row];
            else if (k >= 48 && k < 64) v = Whh1[row * 16 + (k - 48)];
        } else if (w <= 2) {
            int row = g * 32 + (w - 1) * 16 + u;
            if (k < 16)       v = Wih2[row * 16 + k];
            else if (k < 48)  {
                int kk = k - 16;   // 0..31 = [own 0..15 | other 16..31]
                int uu = (w == 1) ? kk : ((kk < 16) ? kk + 16 : kk - 16);
                v = Whh2[row * 32 + uu];
            }
            else if (k == 48) v = bih2[row] + bhh2[row];
        } else {
            int row = g * 16 + u;
            if (k < 32)       v = Wih3[row * 32 + k];
            else if (k < 48)  v = Whh3[row * 16 + (k - 32)];
            else if (k == 48) v = bih3[row] + bhh3[row];
        }
        poolH[idx] = (_Float16)v;
    }
    // head: T2 = W_fc2 @ W_fc1 (fp32; 24KB weights, L2-resident)
    for (int idx = tid; idx < 512; idx += 256) {
        int b = idx >> 4, u = idx & 15;
        float acc = 0.f;
        for (int a = 0; a < 128; ++a) acc += W_fc2[b * 128 + a] * W_fc1[a * 16 + u];
        T2s[idx] = acc;
    }
    if (tid < 32) {
        float acc = b_fc2[tid];
        for (int a = 0; a < 128; ++a) acc += W_fc2[tid * 128 + a] * b_fc1[a];
        t2vs[tid] = acc;
    }
    __syncthreads();

    // ---- per-wave register-resident weight A-frags: lane holds W[mt*16+nl][kt*32+quad*8+j] ----
    hv8 Wf[2][4];
    #pragma unroll
    for (int kt = 0; kt < 2; ++kt)
        #pragma unroll
        for (int mt = 0; mt < 4; ++mt)
            Wf[kt][mt] = *(const hv8*)&poolH[(wid * 64 + mt * 16 + nl) * WS + kt * 32 + quad * 8];
    // collapsed head: M[u][j] = sum_b Wc[j][b]*T2[b][u];  v[j] = bc[j] + sum_b Wc[j][b]*t2v[b]
    if (tid < 96) {
        int u = tid / 6, j = tid - (tid / 6) * 6;
        float acc = 0.f;
        for (int b = 0; b < 32; ++b) acc += W_cls[j * 32 + b] * T2s[b * 16 + u];
        Msh[u * 6 + j] = acc;
    }
    if (tid < 6) {
        float acc = b_cls[tid];
        for (int b = 0; b < 32; ++b) acc += W_cls[tid * 32 + b] * t2vs[b];
        vsh[tid] = acc;
    }
    __syncthreads();   // weights now in registers; pool reusable

    // ---- zero feed slabs (h == 0 for pre-start reads) + prologue x loads (t=0,1) ----
    for (int idx = tid; idx < F_TOTAL; idx += 256) poolH[idx] = (_Float16)0.f;

    fv4 xc[2][3], xn[2][3];            // w0 only: [g][chunk] feats q*8..+3, +4..+7, 32..35
    const float* xb = xg;
    if (wid == 0) {
        int xr = b0 + nl; if (xr > BTOT - 1) xr = BTOT - 1;   // nl 8..15: garbage batch cols, clamped
        xb = xg + (size_t)xr * T_ * 36;
        #pragma unroll
        for (int g = 0; g < 2; ++g) {
            xn[g][0] = *(const fv4*)(xb + g * 36 + quad * 8);
            xn[g][1] = *(const fv4*)(xb + g * 36 + quad * 8 + 4);
            xn[g][2] = *(const fv4*)(xb + g * 36 + 32);
        }
    }
    __syncthreads();

    u32 pk01 = 0, pk23 = 0;                 // own h(t-1), packed fp16 pairs (units q*4+0,1 | +2,3)
    float c_st[4] = {0.f, 0.f, 0.f, 0.f};   // cell state: unit quad*4+r, batch nl
    const int s1x4 = ((quad & 1) * 32 + nl) * 4;   // bpermute byte indices
    const int s2x4 = s1x4 + 64;
    const u32 BIAS1 = 0x00003C00u;          // fp16 1.0 in low half

    const int NI = T_ / 2 + 2;   // 102 barrier intervals, 2 timesteps each
    for (int s = 0; s < NI; ++s) {
        const int pp = (s - 1) & 1, wp = s & 1;
        bool act;
        if (wid == 0)      act = (s < T_ / 2);             // L1: t=2s,2s+1
        else if (wid <= 2) act = (s >= 1 && s <= T_ / 2);  // L2: t=2s-2,2s-1
        else               act = (s >= 2);                 // L3: t=2s-4,2s-3

        HU pf0, pf1, pfx;   // per-interval prefetches (barrier-protected, prev-interval data)
        if (act) {
            if (wid == 0) {
                #pragma unroll
                for (int g = 0; g < 2; ++g) { xc[g][0]=xn[g][0]; xc[g][1]=xn[g][1]; xc[g][2]=xn[g][2]; }
                #pragma unroll
                for (int g = 0; g < 2; ++g) {
                    int t = 2 * s + 2 + g;
                    if (t < T_) {
                        xn[g][0] = *(const fv4*)(xb + t * 36 + quad * 8);
                        xn[g][1] = *(const fv4*)(xb + t * 36 + quad * 8 + 4);
                        xn[g][2] = *(const fv4*)(xb + t * 36 + 32);
                    }
                }
            } else if (wid <= 2) {
                pf0.h = *(const hv8*)&poolH[F1o + ((pp * 2 + 0) * 16 + nl) * 16 + (quad & 1) * 8];
                pf1.h = *(const hv8*)&poolH[F1o + ((pp * 2 + 1) * 16 + nl) * 16 + (quad & 1) * 8];
                // other-half h2 for g0: sibling's slot-1 write from PREVIOUS interval (barrier-safe)
                const int sibX = (wid == 1) ? XBo : XAo;
                pfx.h = *(const hv8*)&poolH[sibX + (1 * 16 + nl) * 16 + (quad & 1) * 8];
            } else {
                pf0.h = *(const hv8*)&poolH[F2o + ((pp * 2 + 0) * 16 + nl) * 32 + quad * 8];
                pf1.h = *(const hv8*)&poolH[F2o + ((pp * 2 + 1) * 16 + nl) * 32 + quad * 8];
            }

            HU x2g1;   // w1/w2: sibling's g0 write this interval (bounded-skew, read issued late)
            #pragma unroll
            for (int g = 0; g < 2; ++g) {
                // recurrence transpose: 4 bpermutes of previous step's packed h
                u32 sA = (u32)__builtin_amdgcn_ds_bpermute(s1x4, (int)pk01);
                u32 sB = (u32)__builtin_amdgcn_ds_bpermute(s1x4, (int)pk23);
                u32 sC = (u32)__builtin_amdgcn_ds_bpermute(s2x4, (int)pk01);
                u32 sD = (u32)__builtin_amdgcn_ds_bpermute(s2x4, (int)pk23);

                HU bk0, bk1;
                if (wid == 0) {
                    // kt0: x feats 0..31 (regs); kt1: q<2 feats 32..35+bias, q>=2 own h1 (shuffles)
                    bk0.u[0] = pk2h(xc[g][0][0], xc[g][0][1]);
                    bk0.u[1] = pk2h(xc[g][0][2], xc[g][0][3]);
                    bk0.u[2] = pk2h(xc[g][1][0], xc[g][1][1]);
                    bk0.u[3] = pk2h(xc[g][1][2], xc[g][1][3]);
                    if (quad >= 2) { bk1.u[0]=sA; bk1.u[1]=sB; bk1.u[2]=sC; bk1.u[3]=sD; }
                    else {
                        bk1.u[0] = pk2h(xc[g][2][0], xc[g][2][1]);
                        bk1.u[1] = pk2h(xc[g][2][2], xc[g][2][3]);
                        bk1.u[2] = BIAS1; bk1.u[3] = 0u;    // k36 bias; k37..39 zero-weight cols
                    }
                } else if (wid <= 2) {
                    // kt0: q<2 h1 feed, q>=2 own h2 (shuffles); kt1: q<2 other h2, q>=2 bias/zero-cols
                    if (quad < 2) bk0 = g ? pf1 : pf0;
                    else { bk0.u[0]=sA; bk0.u[1]=sB; bk0.u[2]=sC; bk0.u[3]=sD; }
                    if (quad < 2) bk1 = g ? x2g1 : pfx;
                    else { bk1.u[0]=BIAS1; bk1.u[1]=0u; bk1.u[2]=0u; bk1.u[3]=0u; }
                } else {
                    // kt0: h2 feed (all quads); kt1: q<2 own h3 (shuffles), q>=2 bias/zero-cols
                    bk0 = g ? pf1 : pf0;
                    if (quad < 2) { bk1.u[0]=sA; bk1.u[1]=sB; bk1.u[2]=sC; bk1.u[3]=sD; }
                    else { bk1.u[0]=BIAS1; bk1.u[1]=0u; bk1.u[2]=0u; bk1.u[3]=0u; }
                }

                fv4 C[4] = {(fv4){0,0,0,0}, (fv4){0,0,0,0}, (fv4){0,0,0,0}, (fv4){0,0,0,0}};
                #pragma unroll
                for (int mt = 0; mt < 4; ++mt) C[mt] = __builtin_amdgcn_mfma_f32_16x16x32_f16(Wf[0][mt], bk0.h, C[mt], 0, 0, 0);
                #pragma unroll
                for (int mt = 0; mt < 4; ++mt) C[mt] = __builtin_amdgcn_mfma_f32_16x16x32_f16(Wf[1][mt], bk1.h, C[mt], 0, 0, 0);

                // C[mt][r] = gate mt (i,f,g,o) for unit quad*4+r, batch nl (bias via const column)
                float h4[4];
                #pragma unroll
                for (int r = 0; r < 4; ++r) {
                    float gi = fsig(C[0][r]);
                    float gf = fsig(C[1][r]);
                    float gg = ftanh(C[2][r]);
                    float go = fsig(C[3][r]);
                    float c  = gf * c_st[r] + gi * gg;
                    c_st[r] = c;
                    h4[r] = go * ftanh(c);
                }
                pk01 = pk2h(h4[0], h4[1]);
                pk23 = pk2h(h4[2], h4[3]);

                // feed writes (off critical path): packed u32 pairs into [batch][unit] slabs
                if (wid == 0) {
                    u32* f1 = (u32*)&poolH[F1o + ((wp * 2 + g) * 16 + nl) * 16 + quad * 4];
                    f1[0] = pk01; f1[1] = pk23;
                } else if (wid <= 2) {
                    const int ownX = (wid == 1) ? XAo : XBo;
                    u32* xo = (u32*)&poolH[ownX + (g * 16 + nl) * 16 + quad * 4];
                    xo[0] = pk01; xo[1] = pk23;
                    const int ub = (wid == 1) ? 0 : 16;
                    u32* f2 = (u32*)&poolH[F2o + ((wp * 2 + g) * 16 + nl) * 32 + ub + quad * 4];
                    f2[0] = pk01; f2[1] = pk23;
                    if (g == 0) {   // read sibling's g0 write for our g1 (issued after own writes)
                        const int sibX = (wid == 1) ? XBo : XAo;
                        x2g1.h = *(const hv8*)&poolH[sibX + (0 * 16 + nl) * 16 + (quad & 1) * 8];
                    }
                } else {
                    u32* f3 = (u32*)&poolH[F3o + (g * 16 + nl) * 16 + quad * 4];
                    f3[0] = pk01; f3[1] = pk23;
                }
            }
        }
        __syncthreads();
    }

    // ---- epilogue: out[b][j] = h3(T-1) . M[:,j] + v[j]   (t=199 -> F3 slot 1) ----
    if (tid < ROWS * 6) {
        int row = tid / 6, j = tid - (tid / 6) * 6;
        float acc = vsh[j];
        const int hb = F3o + 16 * 16 + row * 16;
        #pragma unroll
        for (int u = 0; u < 16; ++u)
            acc += (float)poolH[hb + u] * Msh[u * 6 + j];
        outp[(b0 + row) * 6 + j] = acc;
    }
}

extern "C" void kernel_launch(void* const* d_in, const int* in_sizes, int n_in,
                              void* d_out, int out_size, void* d_ws, size_t ws_size,
                              hipStream_t stream) {
    const float* x     = (const float*)d_in[0];
    const float* Wih1  = (const float*)d_in[1];
    const float* Whh1  = (const float*)d_in[2];
    const float* bih1  = (const float*)d_in[3];
    const float* bhh1  = (const float*)d_in[4];
    const float* Wih2  = (const float*)d_in[5];
    const float* Whh2  = (const float*)d_in[6];
    const float* bih2  = (const float*)d_in[7];
    const float* bhh2  = (const float*)d_in[8];
    const float* Wih3  = (const float*)d_in[9];
    const float* Whh3  = (const float*)d_in[10];
    const float* bih3  = (const float*)d_in[11];
    const float* bhh3  = (const float*)d_in[12];
    const float* W_fc1 = (const float*)d_in[13];
    const float* b_fc1 = (const float*)d_in[14];
    const float* W_fc2 = (const float*)d_in[15];
    const float* b_fc2 = (const float*)d_in[16];
    const float* W_cls = (const float*)d_in[17];
    const float* b_cls = (const float*)d_in[18];

    lstm_fused<<<512, 256, 0, stream>>>(x,
        Wih1, Whh1, bih1, bhh1,
        Wih2, Whh2, bih2, bhh2,
        Wih3, Whh3, bih3, bhh3,
        W_fc1, b_fc1, W_fc2, b_fc2, W_cls, b_cls,
        (float*)d_out);
}